// Round 2
// baseline (370.105 us; speedup 1.0000x reference)
//
#include <hip/hip_runtime.h>
#include <hip/hip_bf16.h>
#include <stdint.h>

#define M_ROWS 4096
#define N_REFS 32768
#define DIM    512
#define NSPLIT 32
#define BM     128
#define CHUNK  128
#define SLICE  (N_REFS / NSPLIT)   // 1024
#define NCHUNKS (SLICE / CHUNK)    // 8

typedef __attribute__((ext_vector_type(8))) short short8;
typedef __attribute__((ext_vector_type(4))) float f32x4;

__device__ __forceinline__ uint32_t f2bf1(float f) {
  uint32_t u = __float_as_uint(f);
  return (u + 0x7FFFu + ((u >> 16) & 1u)) >> 16;   // RNE fp32 -> bf16
}

// One block per row: convert fp32 row -> bf16 (packed), compute sum of squares in fp32.
__global__ void prep_rows(const float* __restrict__ src, uint16_t* __restrict__ dst,
                          float* __restrict__ sq) {
  int row = blockIdx.x;
  int t = threadIdx.x;                       // 256 threads, 2 elems each
  const float2* s = (const float2*)(src + (size_t)row * DIM);
  float2 v = s[t];
  uint32_t packed = f2bf1(v.x) | (f2bf1(v.y) << 16);
  ((uint32_t*)(dst + (size_t)row * DIM))[t] = packed;
  float ss = v.x * v.x + v.y * v.y;
  #pragma unroll
  for (int d = 32; d >= 1; d >>= 1) ss += __shfl_down(ss, d, 64);
  __shared__ float wsum[4];
  int w = t >> 6, lane = t & 63;
  if (lane == 0) wsum[w] = ss;
  __syncthreads();
  if (t == 0) sq[row] = wsum[0] + wsum[1] + wsum[2] + wsum[3];
}

// Main fused kernel: 128x128 output tile, BK=64, 4 waves (2x2), 4x4 16x16x32 MFMA per wave.
// No-max softmax: scores in [-40,-21] are fp32-safe as raw exp. Accumulate per-row
// total and matching-class sums; merge across blocks with atomicAdd.
__global__ __launch_bounds__(256, 4) void ask_main(
    const uint16_t* __restrict__ xbf, const uint16_t* __restrict__ rbf,
    const float* __restrict__ x2, const float* __restrict__ r2,
    const int* __restrict__ y, const int* __restrict__ yref,
    float* __restrict__ totG, float* __restrict__ matchG)
{
  __shared__ unsigned char smem[32768];      // A tile 16KB | B tile 16KB
  unsigned char* sA = smem;
  unsigned char* sB = smem + 16384;

  const int tid  = threadIdx.x;
  const int w    = tid >> 6, lane = tid & 63;
  const int wr   = w >> 1,  wc   = w & 1;
  const int l15  = lane & 15, l4 = lane >> 4;

  const int bm       = blockIdx.x * BM;
  const int colstart = blockIdx.y * SLICE;

  // global_load_lds staging: LDS is linear [128][64] bf16 (128B rows); the XOR
  // swizzle ((row&7)<<4) is applied by permuting the *global source* column.
  const int srow = w * 8 + (lane >> 3);                       // 0..31 per call
  const int scol = ((lane & 7) ^ ((lane >> 3) & 7)) * 8;      // pre-swizzled col
  const uint16_t* gA0 = xbf + (size_t)(bm + srow) * DIM + scol;

  // fragment read offsets (swizzled): addr = row*128 + ((16*l4) ^ ((lane&7)<<4)) ^ (sk<<6)
  const int xorv  = (lane & 7) << 4;
  const int bcol0 = (l4 * 16) ^ xorv;
  int aoff[4], boff[4];
  #pragma unroll
  for (int i = 0; i < 4; ++i) {
    aoff[i] = (wr * 64 + i * 16 + l15) * 128 + bcol0;
    boff[i] = (wc * 64 + i * 16 + l15) * 128 + bcol0;
  }

  // per-lane row metadata: row = bm + wr*64 + mi*16 + l4*4 + r   (i = mi*4+r)
  float x2v[16]; int yv[16];
  #pragma unroll
  for (int i = 0; i < 16; ++i) {
    int row = bm + wr * 64 + (i >> 2) * 16 + l4 * 4 + (i & 3);
    x2v[i] = x2[row];
    yv[i]  = y[row];
  }
  float tot[16], mat[16];
  #pragma unroll
  for (int i = 0; i < 16; ++i) { tot[i] = 0.f; mat[i] = 0.f; }

  for (int ch = 0; ch < NCHUNKS; ++ch) {
    const int colb = colstart + ch * CHUNK;
    const uint16_t* gB0 = rbf + (size_t)(colb + srow) * DIM + scol;

    f32x4 acc[4][4] = {};

    for (int kk = 0; kk < 8; ++kk) {
      const int dk = kk * 64;
      #pragma unroll
      for (int c = 0; c < 4; ++c) {
        __builtin_amdgcn_global_load_lds(
            (const __attribute__((address_space(1))) void*)(gA0 + (size_t)c * 32 * DIM + dk),
            (__attribute__((address_space(3))) void*)(sA + c * 4096 + w * 1024),
            16, 0, 0);
      }
      #pragma unroll
      for (int c = 0; c < 4; ++c) {
        __builtin_amdgcn_global_load_lds(
            (const __attribute__((address_space(1))) void*)(gB0 + (size_t)c * 32 * DIM + dk),
            (__attribute__((address_space(3))) void*)(sB + c * 4096 + w * 1024),
            16, 0, 0);
      }
      __syncthreads();

      #pragma unroll
      for (int sk = 0; sk < 2; ++sk) {
        short8 af[4], bf[4];
        #pragma unroll
        for (int i = 0; i < 4; ++i) af[i] = *(const short8*)(sA + (aoff[i] ^ (sk << 6)));
        #pragma unroll
        for (int i = 0; i < 4; ++i) bf[i] = *(const short8*)(sB + (boff[i] ^ (sk << 6)));
        #pragma unroll
        for (int mi = 0; mi < 4; ++mi)
          #pragma unroll
          for (int ni = 0; ni < 4; ++ni)
            acc[mi][ni] = __builtin_amdgcn_mfma_f32_16x16x32_bf16(af[mi], bf[ni], acc[mi][ni], 0, 0, 0);
      }
      __syncthreads();
    }

    // fused epilogue: e = exp(-sqrt(x2 + r2 - 2*dot)); accumulate total & class-match
    // raw v_sqrt_f32 / v_exp_f32 (no IEEE fixup): ~1e-6 rel err, threshold is ~2%.
    float r2c[4]; int cls[4];
    #pragma unroll
    for (int ni = 0; ni < 4; ++ni) {
      int c = colb + wc * 64 + ni * 16 + l15;
      r2c[ni] = r2[c];
      cls[ni] = yref[c];
    }
    #pragma unroll
    for (int mi = 0; mi < 4; ++mi) {
      #pragma unroll
      for (int r = 0; r < 4; ++r) {
        float xr = x2v[mi * 4 + r];
        int   yy = yv[mi * 4 + r];
        float tsum = 0.f, msum = 0.f;
        #pragma unroll
        for (int ni = 0; ni < 4; ++ni) {
          float t = fmaf(-2.0f, acc[mi][ni][r], xr + r2c[ni]);
          t = fmaxf(t, 0.0f);
          float d = __builtin_amdgcn_sqrtf(t);
          float e = __builtin_amdgcn_exp2f(-1.44269504088896f * d);
          tsum += e;
          msum += (cls[ni] == yy) ? e : 0.0f;
        }
        tot[mi * 4 + r] += tsum;
        mat[mi * 4 + r] += msum;
      }
    }
  }

  // reduce across the 16 lanes (l15) that share each row, then merge globally
  #pragma unroll
  for (int i = 0; i < 16; ++i) {
    float t = tot[i], m = mat[i];
    #pragma unroll
    for (int d = 1; d <= 8; d <<= 1) {
      t += __shfl_xor(t, d, 64);
      m += __shfl_xor(m, d, 64);
    }
    if (l15 == 0) {
      int row = bm + wr * 64 + (i >> 2) * 16 + l4 * 4 + (i & 3);
      atomicAdd(&totG[row], t);
      atomicAdd(&matchG[row], m);
    }
  }
}

__global__ void finalize_loss(const float* __restrict__ totG, const float* __restrict__ matchG,
                              float* __restrict__ out) {
  __shared__ float red[256];
  int t = threadIdx.x;
  float s = 0.f;
  for (int r = t; r < M_ROWS; r += 256)
    s += logf(matchG[r] / totG[r] + 1e-6f);
  red[t] = s;
  __syncthreads();
  for (int off = 128; off >= 1; off >>= 1) {
    if (t < off) red[t] += red[t + off];
    __syncthreads();
  }
  if (t == 0) out[0] = -red[0] / (float)M_ROWS;
}

extern "C" void kernel_launch(void* const* d_in, const int* in_sizes, int n_in,
                              void* d_out, int out_size, void* d_ws, size_t ws_size,
                              hipStream_t stream) {
  const float* x    = (const float*)d_in[0];
  const float* xref = (const float*)d_in[1];
  const int*   y    = (const int*)d_in[2];
  const int*   yref = (const int*)d_in[3];
  float* out = (float*)d_out;

  uint8_t* ws = (uint8_t*)d_ws;
  uint16_t* xbf   = (uint16_t*)(ws);                    //  4 MB
  uint16_t* rbf   = (uint16_t*)(ws + 4194304);          // 32 MB
  float*    x2    = (float*)(ws + 37748736);            // 16 KB
  float*    r2    = (float*)(ws + 37765120);            // 128 KB
  float*    totG  = (float*)(ws + 37896192);            // 16 KB
  float*    matchG= (float*)(ws + 37912576);            // 16 KB

  hipMemsetAsync(totG, 0, 2 * M_ROWS * sizeof(float), stream);

  prep_rows<<<M_ROWS, 256, 0, stream>>>(x, xbf, x2);
  prep_rows<<<N_REFS, 256, 0, stream>>>(xref, rbf, r2);
  ask_main<<<dim3(M_ROWS / BM, NSPLIT), 256, 0, stream>>>(xbf, rbf, x2, r2, y, yref, totG, matchG);
  finalize_loss<<<1, 256, 0, stream>>>(totG, matchG, out);
}

// Round 3
// 213.574 us; speedup vs baseline: 1.7329x; 1.7329x over previous
//
#include <hip/hip_runtime.h>
#include <hip/hip_bf16.h>
#include <stdint.h>

#define M_ROWS 4096
#define N_REFS 32768
#define DIM    512
#define NSPLIT 32
#define BM     128
#define CHUNK  128
#define SLICE  (N_REFS / NSPLIT)   // 1024
#define NCHUNKS (SLICE / CHUNK)    // 8

typedef __attribute__((ext_vector_type(8))) short short8;
typedef __attribute__((ext_vector_type(4))) float f32x4;

__device__ __forceinline__ uint32_t f2bf1(float f) {
  uint32_t u = __float_as_uint(f);
  return (u + 0x7FFFu + ((u >> 16) & 1u)) >> 16;   // RNE fp32 -> bf16
}

// One block per row: convert fp32 row -> bf16 (packed), compute sum of squares in fp32.
__global__ void prep_rows(const float* __restrict__ src, uint16_t* __restrict__ dst,
                          float* __restrict__ sq) {
  int row = blockIdx.x;
  int t = threadIdx.x;                       // 256 threads, 2 elems each
  const float2* s = (const float2*)(src + (size_t)row * DIM);
  float2 v = s[t];
  uint32_t packed = f2bf1(v.x) | (f2bf1(v.y) << 16);
  ((uint32_t*)(dst + (size_t)row * DIM))[t] = packed;
  float ss = v.x * v.x + v.y * v.y;
  #pragma unroll
  for (int d = 32; d >= 1; d >>= 1) ss += __shfl_down(ss, d, 64);
  __shared__ float wsum[4];
  int w = t >> 6, lane = t & 63;
  if (lane == 0) wsum[w] = ss;
  __syncthreads();
  if (t == 0) sq[row] = wsum[0] + wsum[1] + wsum[2] + wsum[3];
}

// Main fused kernel: 128x128 output tile, BK=64, 4 waves (2x2), 4x4 16x16x32 MFMA per wave.
// No-max softmax: scores in [-40,-21] are fp32-safe as raw exp. Accumulate per-row
// total and matching-class sums; merge across blocks with atomicAdd.
// NOTE: (256,2) not (256,4) — the tighter bound capped VGPR at 64 and spilled
// the 64-VGPR accumulator to scratch (R2: WRITE_SIZE 4->397MB, dur +50%).
__global__ __launch_bounds__(256, 2) void ask_main(
    const uint16_t* __restrict__ xbf, const uint16_t* __restrict__ rbf,
    const float* __restrict__ x2, const float* __restrict__ r2,
    const int* __restrict__ y, const int* __restrict__ yref,
    float* __restrict__ totG, float* __restrict__ matchG)
{
  __shared__ unsigned char smem[32768];      // A tile 16KB | B tile 16KB
  unsigned char* sA = smem;
  unsigned char* sB = smem + 16384;

  const int tid  = threadIdx.x;
  const int w    = tid >> 6, lane = tid & 63;
  const int wr   = w >> 1,  wc   = w & 1;
  const int l15  = lane & 15, l4 = lane >> 4;

  const int bm       = blockIdx.x * BM;
  const int colstart = blockIdx.y * SLICE;

  // global_load_lds staging: LDS is linear [128][64] bf16 (128B rows); the XOR
  // swizzle ((row&7)<<4) is applied by permuting the *global source* column.
  const int srow = w * 8 + (lane >> 3);                       // 0..31 per call
  const int scol = ((lane & 7) ^ ((lane >> 3) & 7)) * 8;      // pre-swizzled col
  const uint16_t* gA0 = xbf + (size_t)(bm + srow) * DIM + scol;

  // fragment read offsets (swizzled): addr = row*128 + ((16*l4) ^ ((lane&7)<<4)) ^ (sk<<6)
  const int xorv  = (lane & 7) << 4;
  const int bcol0 = (l4 * 16) ^ xorv;
  int aoff[4], boff[4];
  #pragma unroll
  for (int i = 0; i < 4; ++i) {
    aoff[i] = (wr * 64 + i * 16 + l15) * 128 + bcol0;
    boff[i] = (wc * 64 + i * 16 + l15) * 128 + bcol0;
  }

  // per-lane row metadata: row = bm + wr*64 + mi*16 + l4*4 + r   (i = mi*4+r)
  float x2v[16]; int yv[16];
  #pragma unroll
  for (int i = 0; i < 16; ++i) {
    int row = bm + wr * 64 + (i >> 2) * 16 + l4 * 4 + (i & 3);
    x2v[i] = x2[row];
    yv[i]  = y[row];
  }
  float tot[16], mat[16];
  #pragma unroll
  for (int i = 0; i < 16; ++i) { tot[i] = 0.f; mat[i] = 0.f; }

  for (int ch = 0; ch < NCHUNKS; ++ch) {
    const int colb = colstart + ch * CHUNK;
    const uint16_t* gB0 = rbf + (size_t)(colb + srow) * DIM + scol;

    f32x4 acc[4][4] = {};

    for (int kk = 0; kk < 8; ++kk) {
      const int dk = kk * 64;
      #pragma unroll
      for (int c = 0; c < 4; ++c) {
        __builtin_amdgcn_global_load_lds(
            (const __attribute__((address_space(1))) void*)(gA0 + (size_t)c * 32 * DIM + dk),
            (__attribute__((address_space(3))) void*)(sA + c * 4096 + w * 1024),
            16, 0, 0);
      }
      #pragma unroll
      for (int c = 0; c < 4; ++c) {
        __builtin_amdgcn_global_load_lds(
            (const __attribute__((address_space(1))) void*)(gB0 + (size_t)c * 32 * DIM + dk),
            (__attribute__((address_space(3))) void*)(sB + c * 4096 + w * 1024),
            16, 0, 0);
      }
      __syncthreads();

      #pragma unroll
      for (int sk = 0; sk < 2; ++sk) {
        short8 af[4], bf[4];
        #pragma unroll
        for (int i = 0; i < 4; ++i) af[i] = *(const short8*)(sA + (aoff[i] ^ (sk << 6)));
        #pragma unroll
        for (int i = 0; i < 4; ++i) bf[i] = *(const short8*)(sB + (boff[i] ^ (sk << 6)));
        #pragma unroll
        for (int mi = 0; mi < 4; ++mi)
          #pragma unroll
          for (int ni = 0; ni < 4; ++ni)
            acc[mi][ni] = __builtin_amdgcn_mfma_f32_16x16x32_bf16(af[mi], bf[ni], acc[mi][ni], 0, 0, 0);
      }
      __syncthreads();
    }

    // fused epilogue: e = exp(-sqrt(x2 + r2 - 2*dot)); accumulate total & class-match
    // raw v_sqrt_f32 / v_exp_f32 (no IEEE fixup): ~1e-6 rel err, threshold is ~2%.
    float r2c[4]; int cls[4];
    #pragma unroll
    for (int ni = 0; ni < 4; ++ni) {
      int c = colb + wc * 64 + ni * 16 + l15;
      r2c[ni] = r2[c];
      cls[ni] = yref[c];
    }
    #pragma unroll
    for (int mi = 0; mi < 4; ++mi) {
      #pragma unroll
      for (int r = 0; r < 4; ++r) {
        float xr = x2v[mi * 4 + r];
        int   yy = yv[mi * 4 + r];
        float tsum = 0.f, msum = 0.f;
        #pragma unroll
        for (int ni = 0; ni < 4; ++ni) {
          float t = fmaf(-2.0f, acc[mi][ni][r], xr + r2c[ni]);
          t = fmaxf(t, 0.0f);
          float d = __builtin_amdgcn_sqrtf(t);
          float e = __builtin_amdgcn_exp2f(-1.44269504088896f * d);
          tsum += e;
          msum += (cls[ni] == yy) ? e : 0.0f;
        }
        tot[mi * 4 + r] += tsum;
        mat[mi * 4 + r] += msum;
      }
    }
  }

  // reduce across the 16 lanes (l15) that share each row, then merge globally
  #pragma unroll
  for (int i = 0; i < 16; ++i) {
    float t = tot[i], m = mat[i];
    #pragma unroll
    for (int d = 1; d <= 8; d <<= 1) {
      t += __shfl_xor(t, d, 64);
      m += __shfl_xor(m, d, 64);
    }
    if (l15 == 0) {
      int row = bm + wr * 64 + (i >> 2) * 16 + l4 * 4 + (i & 3);
      atomicAdd(&totG[row], t);
      atomicAdd(&matchG[row], m);
    }
  }
}

__global__ void finalize_loss(const float* __restrict__ totG, const float* __restrict__ matchG,
                              float* __restrict__ out) {
  __shared__ float red[256];
  int t = threadIdx.x;
  float s = 0.f;
  for (int r = t; r < M_ROWS; r += 256)
    s += logf(matchG[r] / totG[r] + 1e-6f);
  red[t] = s;
  __syncthreads();
  for (int off = 128; off >= 1; off >>= 1) {
    if (t < off) red[t] += red[t + off];
    __syncthreads();
  }
  if (t == 0) out[0] = -red[0] / (float)M_ROWS;
}

extern "C" void kernel_launch(void* const* d_in, const int* in_sizes, int n_in,
                              void* d_out, int out_size, void* d_ws, size_t ws_size,
                              hipStream_t stream) {
  const float* x    = (const float*)d_in[0];
  const float* xref = (const float*)d_in[1];
  const int*   y    = (const int*)d_in[2];
  const int*   yref = (const int*)d_in[3];
  float* out = (float*)d_out;

  uint8_t* ws = (uint8_t*)d_ws;
  uint16_t* xbf   = (uint16_t*)(ws);                    //  4 MB
  uint16_t* rbf   = (uint16_t*)(ws + 4194304);          // 32 MB
  float*    x2    = (float*)(ws + 37748736);            // 16 KB
  float*    r2    = (float*)(ws + 37765120);            // 128 KB
  float*    totG  = (float*)(ws + 37896192);            // 16 KB
  float*    matchG= (float*)(ws + 37912576);            // 16 KB

  hipMemsetAsync(totG, 0, 2 * M_ROWS * sizeof(float), stream);

  prep_rows<<<M_ROWS, 256, 0, stream>>>(x, xbf, x2);
  prep_rows<<<N_REFS, 256, 0, stream>>>(xref, rbf, r2);
  ask_main<<<dim3(M_ROWS / BM, NSPLIT), 256, 0, stream>>>(xbf, rbf, x2, r2, y, yref, totG, matchG);
  finalize_loss<<<1, 256, 0, stream>>>(totG, matchG, out);
}